// Round 5
// baseline (233.284 us; speedup 1.0000x reference)
//
#include <hip/hip_runtime.h>

typedef __bf16 bf16x8 __attribute__((ext_vector_type(8)));
typedef float f32x4 __attribute__((ext_vector_type(4)));
typedef unsigned short u16;

#define IN_F 4096
#define OUT_F 4096
#define NTOK 4096
#define RANK 32
#define KEXT 4160              /* 4096 + 32 lora cols + 32 zero pad -> 65 K-tiles of 64 */
#define NT (KEXT / 64)         /* 65 */
#define ROWB ((size_t)KEXT * 2) /* row stride bytes = 8320 */

// round-to-nearest-even f32 -> bf16
__device__ __forceinline__ u16 f2bf(float f) {
  union { float f; unsigned u; } c; c.f = f;
  unsigned u = c.u;
  return (u16)((u + 0x7FFFu + ((u >> 16) & 1u)) >> 16);
}

__device__ __forceinline__ void gload_lds16(const void* g, void* l) {
  __builtin_amdgcn_global_load_lds((const __attribute__((address_space(1))) void*)g,
                                   (__attribute__((address_space(3))) void*)l,
                                   16, 0, 0);
}

// ---------------- prep: per-token amax -> ascale, write bf16 int codes + zero pad ----------------
__global__ __launch_bounds__(256) void prep_kernel(const float* __restrict__ x,
                                                   u16* __restrict__ A,
                                                   float* __restrict__ ascale) {
  int t = blockIdx.x;
  int tid = threadIdx.x;
  const float4* xr = (const float4*)(x + (size_t)t * IN_F);
  float4 v[4];
  float m = 0.f;
#pragma unroll
  for (int i = 0; i < 4; ++i) {
    v[i] = xr[tid + i * 256];
    m = fmaxf(m, fmaxf(fmaxf(fabsf(v[i].x), fabsf(v[i].y)),
                       fmaxf(fabsf(v[i].z), fabsf(v[i].w))));
  }
#pragma unroll
  for (int off = 32; off > 0; off >>= 1) m = fmaxf(m, __shfl_xor(m, off));
  __shared__ float wmax[4];
  if ((tid & 63) == 0) wmax[tid >> 6] = m;
  __syncthreads();
  m = fmaxf(fmaxf(wmax[0], wmax[1]), fmaxf(wmax[2], wmax[3]));
  float as = fmaxf(m, 1e-6f) / 7.f;
  float inv = 1.f / as;
  if (tid == 0) ascale[t] = as;
  u16* Ar = A + (size_t)t * KEXT;
#pragma unroll
  for (int i = 0; i < 4; ++i) {
    float q0 = fminf(fmaxf(rintf(v[i].x * inv), -8.f), 7.f);
    float q1 = fminf(fmaxf(rintf(v[i].y * inv), -8.f), 7.f);
    float q2 = fminf(fmaxf(rintf(v[i].z * inv), -8.f), 7.f);
    float q3 = fminf(fmaxf(rintf(v[i].w * inv), -8.f), 7.f);
    ushort4 u;
    u.x = f2bf(q0); u.y = f2bf(q1); u.z = f2bf(q2); u.w = f2bf(q3);
    *(ushort4*)(Ar + (size_t)(tid + i * 256) * 4) = u;
  }
  if (tid < 8) {  // zero pad cols 4128..4159
    ushort4 z; z.x = z.y = z.z = z.w = 0;
    *(ushort4*)(Ar + IN_F + 32 + tid * 4) = z;
  }
}

// ---------------- dequant: int4 codes * group scale -> bf16, append lora_up + zero pad ----------------
__global__ __launch_bounds__(256) void dequant_kernel(const int* __restrict__ qw,
                                                      const float* __restrict__ wscale,
                                                      const float* __restrict__ lu,
                                                      u16* __restrict__ B) {
  int o = blockIdx.x;
  int tid = threadIdx.x;
  const int4* qr = (const int4*)(qw + (size_t)o * IN_F);
  const float* sr = wscale + (size_t)o * (IN_F / 64);
  u16* Br = B + (size_t)o * KEXT;
#pragma unroll
  for (int s = 0; s < 4; ++s) {
    int e = tid + s * 256;
    int4 q = qr[e];
    float sc = sr[e >> 4];
    ushort4 u;
    u.x = f2bf((float)q.x * sc);
    u.y = f2bf((float)q.y * sc);
    u.z = f2bf((float)q.z * sc);
    u.w = f2bf((float)q.w * sc);
    *(ushort4*)(Br + (size_t)4 * e) = u;
  }
  if (tid < RANK) Br[IN_F + tid] = f2bf(lu[(size_t)o * RANK + tid]);
  if (tid < 8) {
    ushort4 z; z.x = z.y = z.z = z.w = 0;
    *(ushort4*)(Br + IN_F + 32 + tid * 4) = z;
  }
}

// ---------------- lorad: tr = x @ ld^T, split-K=8 partials ----------------
__global__ __launch_bounds__(256) void lorad_kernel(const float* __restrict__ x,
                                                    const float* __restrict__ ld,
                                                    float* __restrict__ tr8) {
  __shared__ float Xs[128][68];
  __shared__ float Ls[32][68];
  int b = blockIdx.x;
  int t0 = (b >> 3) * 128;
  int kbase = (b & 7) * 512;
  int tid = threadIdx.x;
  int rb = tid & 7;
  int tb = tid >> 3;
  float acc[4][4];
#pragma unroll
  for (int i = 0; i < 4; ++i)
#pragma unroll
    for (int j = 0; j < 4; ++j) acc[i][j] = 0.f;

  for (int kc = 0; kc < 512; kc += 64) {
    int k0 = kbase + kc;
    __syncthreads();
#pragma unroll
    for (int s = 0; s < 8; ++s) {
      int e = tid + s * 256;
      int row = e >> 4, c4 = (e & 15) * 4;
      float4 vv = *(const float4*)(x + (size_t)(t0 + row) * IN_F + k0 + c4);
      *(float4*)&Xs[row][c4] = vv;
    }
#pragma unroll
    for (int s = 0; s < 2; ++s) {
      int e = tid + s * 256;
      int row = e >> 4, c4 = (e & 15) * 4;
      float4 vv = *(const float4*)(ld + (size_t)row * IN_F + k0 + c4);
      *(float4*)&Ls[row][c4] = vv;
    }
    __syncthreads();
    for (int k4 = 0; k4 < 64; k4 += 4) {
      float4 lv[4], xv[4];
#pragma unroll
      for (int r = 0; r < 4; ++r) lv[r] = *(float4*)&Ls[rb + r * 8][k4];
#pragma unroll
      for (int mm = 0; mm < 4; ++mm) xv[mm] = *(float4*)&Xs[tb + mm * 32][k4];
#pragma unroll
      for (int mm = 0; mm < 4; ++mm)
#pragma unroll
        for (int r = 0; r < 4; ++r)
          acc[mm][r] += xv[mm].x * lv[r].x + xv[mm].y * lv[r].y +
                        xv[mm].z * lv[r].z + xv[mm].w * lv[r].w;
    }
  }
  float* dst = tr8 + (size_t)(b & 7) * NTOK * RANK;
#pragma unroll
  for (int mm = 0; mm < 4; ++mm)
#pragma unroll
    for (int r = 0; r < 4; ++r)
      dst[(size_t)(t0 + tb + mm * 32) * RANK + rb + r * 8] = acc[mm][r];
}

// ---------------- trwrite ----------------
__global__ __launch_bounds__(256) void trwrite_kernel(const float* __restrict__ tr8,
                                                      const float* __restrict__ ascale,
                                                      u16* __restrict__ A) {
  int idx = blockIdx.x * 256 + threadIdx.x;
  int t = idx >> 5, r = idx & 31;
  float s = 0.f;
#pragma unroll
  for (int k = 0; k < 8; ++k) s += tr8[(size_t)k * NTOK * RANK + idx];
  A[(size_t)t * KEXT + IN_F + r] = f2bf(s / ascale[t]);
}

// ---------------- main GEMM: 128x128 tile, BK=64, 4 waves, 2 blocks/CU ----------------
// Retile of the round-4 free-flow schedule: same 128B row stride, same
// XOR(row&7) swizzle (0 conflicts), same 3-barrier hazard proof, same vmcnt(8)
// invariant (each stage_tile = 4 gload_lds). LDS = 64KB -> 2 blocks/CU so the
// 2 waves/SIMD come from INDEPENDENT barrier domains: one block's barrier
// convoy / tile-start read burst is hidden under the other block's MFMAs.
// Read order af01, bf01, af23, bf23 (DS completes in order per wave):
//  - Q1 consumes reads 1-8 -> startup stall = 8-read drain.
//  - Q2 consumes af[2-3] (reads 9-12) => all A-region reads drained post-Q2
//    -> barrier -> stage A(t+2) into buf c is WAR-safe.
//  - Q3 consumes bf[2-3] (reads 13-16, last) => all B reads drained post-Q3
//    -> barrier -> stage B(t+2); vmcnt(8) leaves exactly t+2's 8 loads in
//    flight => t+1 landed (own wave); end barrier makes it global.

__device__ __forceinline__ void stage_tile(const char* g, char* ldst, int tid) {
#pragma unroll
  for (int h = 0; h < 4; ++h)
    gload_lds16(g + (size_t)h * (32 * ROWB), ldst + h * 4096 + tid * 16);
}

#define PIN_BARRIER() do { __builtin_amdgcn_sched_barrier(0); \
                           asm volatile("s_barrier" ::: "memory"); } while (0)

__global__ __launch_bounds__(256, 2) void gemm_kernel(const u16* __restrict__ A,
                                                      const u16* __restrict__ B,
                                                      const float* __restrict__ ascale,
                                                      const float* __restrict__ bias,
                                                      float* __restrict__ out) {
  __shared__ __align__(16) char smem[65536];
  int b = blockIdx.x;
  int swz = (b & 7) * 128 + (b >> 3);    // 1024 blocks, 8 XCDs -> bijective
  int by = swz >> 5, bx = swz & 31;
  int tm = by * 128, tn = bx * 128;
  int tid = threadIdx.x;
  int lane = tid & 63, wid = tid >> 6;
  int wr = wid >> 1, wc = wid & 1;       // 2x2 wave grid; wave owns 64x64 of C
  int l15 = lane & 15, l4 = lane >> 4;
  int xorb = (l15 & 7) << 4;             // row&7 -> 16B-chunk XOR (bits 4-6)
  int colx0 = (l4 * 16) ^ xorb;          // K elements l4*8 .. +7
  int colx1 = (l4 * 16 + 64) ^ xorb;     // K elements 32+l4*8 .. +7
  int a_base = wr * 8192 + l15 * 128;    // row = wr*64 + i*16 + l15
  int b_base = wc * 8192 + l15 * 128;    // row = wc*64 + j*16 + l15

  // staging: thread tid writes LDS bytes [h*4096 + tid*16); source column chunk
  // is (tid&7) ^ (row&7), row = tid>>3 within the 32-row h-block.
  int r0 = tid >> 3;
  int cb = (((tid & 7) ^ ((tid >> 3) & 7)) << 4);
  const char* ag = (const char*)A + (size_t)(tm + r0) * ROWB + cb;
  const char* bg = (const char*)B + (size_t)(tn + r0) * ROWB + cb;

  f32x4 acc[4][4];
#pragma unroll
  for (int i = 0; i < 4; ++i)
#pragma unroll
    for (int j = 0; j < 4; ++j) acc[i][j] = (f32x4){0.f, 0.f, 0.f, 0.f};

  // prologue: stage tiles 0 (buf0) and 1 (buf1). A buf c at c*16384; B at 32768+c*16384.
  stage_tile(ag, smem, tid);
  stage_tile(bg, smem + 32768, tid);
  stage_tile(ag + 128, smem + 16384, tid);
  stage_tile(bg + 128, smem + 32768 + 16384, tid);
  asm volatile("s_waitcnt vmcnt(8)" ::: "memory");  // tile 0 landed; tile 1 in flight
  PIN_BARRIER();

  const char* apf = ag + 256;  // tile t+2 source (t=0)
  const char* bpf = bg + 256;
  bf16x8 af[4][2], bf[4][2];

  for (int t = 0; t < NT; ++t) {
    int c = t & 1;
    int ao = c * 16384 + a_base;
    int bo = 32768 + c * 16384 + b_base;
    bool pf = (t + 2) < NT;

    // ---- issue all fragment reads (order is the hazard proof) ----
#pragma unroll
    for (int i = 0; i < 2; ++i) {
      af[i][0] = *(const bf16x8*)(smem + ao + i * 2048 + colx0);
      af[i][1] = *(const bf16x8*)(smem + ao + i * 2048 + colx1);
    }
#pragma unroll
    for (int j = 0; j < 2; ++j) {
      bf[j][0] = *(const bf16x8*)(smem + bo + j * 2048 + colx0);
      bf[j][1] = *(const bf16x8*)(smem + bo + j * 2048 + colx1);
    }
#pragma unroll
    for (int i = 2; i < 4; ++i) {
      af[i][0] = *(const bf16x8*)(smem + ao + i * 2048 + colx0);
      af[i][1] = *(const bf16x8*)(smem + ao + i * 2048 + colx1);
    }
#pragma unroll
    for (int j = 2; j < 4; ++j) {
      bf[j][0] = *(const bf16x8*)(smem + bo + j * 2048 + colx0);
      bf[j][1] = *(const bf16x8*)(smem + bo + j * 2048 + colx1);
    }

    // ---- Q1: i0-1 x j0-1 ----
    __builtin_amdgcn_s_setprio(1);
#pragma unroll
    for (int i = 0; i < 2; ++i)
#pragma unroll
      for (int j = 0; j < 2; ++j) {
        acc[i][j] = __builtin_amdgcn_mfma_f32_16x16x32_bf16(af[i][0], bf[j][0], acc[i][j], 0, 0, 0);
        acc[i][j] = __builtin_amdgcn_mfma_f32_16x16x32_bf16(af[i][1], bf[j][1], acc[i][j], 0, 0, 0);
      }
    __builtin_amdgcn_s_setprio(0);

    // ---- Q2: i2-3 x j0-1 (consumes af[2-3] => all A reads drained) ----
    __builtin_amdgcn_s_setprio(1);
#pragma unroll
    for (int i = 2; i < 4; ++i)
#pragma unroll
      for (int j = 0; j < 2; ++j) {
        acc[i][j] = __builtin_amdgcn_mfma_f32_16x16x32_bf16(af[i][0], bf[j][0], acc[i][j], 0, 0, 0);
        acc[i][j] = __builtin_amdgcn_mfma_f32_16x16x32_bf16(af[i][1], bf[j][1], acc[i][j], 0, 0, 0);
      }
    __builtin_amdgcn_s_setprio(0);
    PIN_BARRIER();                         // A-region of buf c free in ALL waves
    if (pf) stage_tile(apf, smem + c * 16384, tid);

    // ---- Q3: i0-1 x j2-3 (consumes bf[2-3] => all reads drained) ----
    __builtin_amdgcn_s_setprio(1);
#pragma unroll
    for (int i = 0; i < 2; ++i)
#pragma unroll
      for (int j = 2; j < 4; ++j) {
        acc[i][j] = __builtin_amdgcn_mfma_f32_16x16x32_bf16(af[i][0], bf[j][0], acc[i][j], 0, 0, 0);
        acc[i][j] = __builtin_amdgcn_mfma_f32_16x16x32_bf16(af[i][1], bf[j][1], acc[i][j], 0, 0, 0);
      }
    __builtin_amdgcn_s_setprio(0);
    PIN_BARRIER();                         // B-region of buf c free in ALL waves
    if (pf) {
      stage_tile(bpf, smem + 32768 + c * 16384, tid);
      asm volatile("s_waitcnt vmcnt(8)" ::: "memory");  // t+1 landed; t+2 in flight
    } else if (t == NT - 2) {
      asm volatile("s_waitcnt vmcnt(0)" ::: "memory");  // tail drain for tile NT-1
    }

    // ---- Q4: i2-3 x j2-3 ----
    __builtin_amdgcn_s_setprio(1);
#pragma unroll
    for (int i = 2; i < 4; ++i)
#pragma unroll
      for (int j = 2; j < 4; ++j) {
        acc[i][j] = __builtin_amdgcn_mfma_f32_16x16x32_bf16(af[i][0], bf[j][0], acc[i][j], 0, 0, 0);
        acc[i][j] = __builtin_amdgcn_mfma_f32_16x16x32_bf16(af[i][1], bf[j][1], acc[i][j], 0, 0, 0);
      }
    __builtin_amdgcn_s_setprio(0);
    PIN_BARRIER();                         // all waves saw their vmcnt before t+1 reads

    apf += 128;
    bpf += 128;
  }

  // ---- epilogue: C = acc * ascale[row] + bias[col] ----
#pragma unroll
  for (int i = 0; i < 4; ++i) {
    int rowb = tm + wr * 64 + i * 16 + l4 * 4;
#pragma unroll
    for (int j = 0; j < 4; ++j) {
      int col = tn + wc * 64 + j * 16 + l15;
      float bv = bias[col];
#pragma unroll
      for (int q = 0; q < 4; ++q)
        out[(size_t)(rowb + q) * OUT_F + col] = acc[i][j][q] * ascale[rowb + q] + bv;
    }
  }
}

extern "C" void kernel_launch(void* const* d_in, const int* in_sizes, int n_in,
                              void* d_out, int out_size, void* d_ws, size_t ws_size,
                              hipStream_t stream) {
  const float* x = (const float*)d_in[0];
  const int* qw = (const int*)d_in[1];
  const float* wscale = (const float*)d_in[2];
  const float* ld = (const float*)d_in[3];
  const float* lu = (const float*)d_in[4];
  const float* bias = (const float*)d_in[5];
  float* out = (float*)d_out;

  char* ws = (char*)d_ws;
  const size_t szA = (size_t)NTOK * KEXT * sizeof(u16);
  const size_t szB = (size_t)OUT_F * KEXT * sizeof(u16);
  u16* Aext = (u16*)ws;
  u16* Bext = (u16*)(ws + szA);
  float* ascale = (float*)(ws + szA + szB);
  float* tr8 = (float*)(ws + szA + szB + 16384);

  prep_kernel<<<NTOK, 256, 0, stream>>>(x, Aext, ascale);
  dequant_kernel<<<OUT_F, 256, 0, stream>>>(qw, wscale, lu, Bext);
  lorad_kernel<<<256, 256, 0, stream>>>(x, ld, tr8);
  trwrite_kernel<<<NTOK * RANK / 256, 256, 0, stream>>>(tr8, ascale, Aext);
  gemm_kernel<<<(NTOK / 128) * (OUT_F / 128), 256, 0, stream>>>(Aext, Bext, ascale, bias, out);
}

// Round 6
// 185.473 us; speedup vs baseline: 1.2578x; 1.2578x over previous
//
#include <hip/hip_runtime.h>

typedef __bf16 bf16x8 __attribute__((ext_vector_type(8)));
typedef float f32x4 __attribute__((ext_vector_type(4)));
typedef unsigned short u16;

#define IN_F 4096
#define OUT_F 4096
#define NTOK 4096
#define RANK 32
#define KEXT 4160              /* 4096 + 32 lora cols + 32 zero pad -> 65 K-tiles of 64 */
#define NT 65
#define ROWB ((size_t)KEXT * 2) /* row stride bytes = 8320 */
#define D1 65536               /* LDS byte offset of dbuf1 */

// round-to-nearest-even f32 -> bf16
__device__ __forceinline__ u16 f2bf(float f) {
  union { float f; unsigned u; } c; c.f = f;
  unsigned u = c.u;
  return (u16)((u + 0x7FFFu + ((u >> 16) & 1u)) >> 16);
}

__device__ __forceinline__ void gload_lds16(const void* g, void* l) {
  __builtin_amdgcn_global_load_lds((const __attribute__((address_space(1))) void*)g,
                                   (__attribute__((address_space(3))) void*)l,
                                   16, 0, 0);
}

// ---------------- prep: per-token amax -> ascale, write bf16 int codes + zero pad ----------------
__global__ __launch_bounds__(256) void prep_kernel(const float* __restrict__ x,
                                                   u16* __restrict__ A,
                                                   float* __restrict__ ascale) {
  int t = blockIdx.x;
  int tid = threadIdx.x;
  const float4* xr = (const float4*)(x + (size_t)t * IN_F);
  float4 v[4];
  float m = 0.f;
#pragma unroll
  for (int i = 0; i < 4; ++i) {
    v[i] = xr[tid + i * 256];
    m = fmaxf(m, fmaxf(fmaxf(fabsf(v[i].x), fabsf(v[i].y)),
                       fmaxf(fabsf(v[i].z), fabsf(v[i].w))));
  }
#pragma unroll
  for (int off = 32; off > 0; off >>= 1) m = fmaxf(m, __shfl_xor(m, off));
  __shared__ float wmax[4];
  if ((tid & 63) == 0) wmax[tid >> 6] = m;
  __syncthreads();
  m = fmaxf(fmaxf(wmax[0], wmax[1]), fmaxf(wmax[2], wmax[3]));
  float as = fmaxf(m, 1e-6f) / 7.f;
  float inv = 1.f / as;
  if (tid == 0) ascale[t] = as;
  u16* Ar = A + (size_t)t * KEXT;
#pragma unroll
  for (int i = 0; i < 4; ++i) {
    float q0 = fminf(fmaxf(rintf(v[i].x * inv), -8.f), 7.f);
    float q1 = fminf(fmaxf(rintf(v[i].y * inv), -8.f), 7.f);
    float q2 = fminf(fmaxf(rintf(v[i].z * inv), -8.f), 7.f);
    float q3 = fminf(fmaxf(rintf(v[i].w * inv), -8.f), 7.f);
    ushort4 u;
    u.x = f2bf(q0); u.y = f2bf(q1); u.z = f2bf(q2); u.w = f2bf(q3);
    *(ushort4*)(Ar + (size_t)(tid + i * 256) * 4) = u;
  }
  if (tid < 8) {  // zero pad cols 4128..4159
    ushort4 z; z.x = z.y = z.z = z.w = 0;
    *(ushort4*)(Ar + IN_F + 32 + tid * 4) = z;
  }
}

// ---------------- dequant: int4 codes * group scale -> bf16, append lora_up + zero pad ----------------
__global__ __launch_bounds__(256) void dequant_kernel(const int* __restrict__ qw,
                                                      const float* __restrict__ wscale,
                                                      const float* __restrict__ lu,
                                                      u16* __restrict__ B) {
  int o = blockIdx.x;
  int tid = threadIdx.x;
  const int4* qr = (const int4*)(qw + (size_t)o * IN_F);
  const float* sr = wscale + (size_t)o * (IN_F / 64);
  u16* Br = B + (size_t)o * KEXT;
#pragma unroll
  for (int s = 0; s < 4; ++s) {
    int e = tid + s * 256;
    int4 q = qr[e];
    float sc = sr[e >> 4];
    ushort4 u;
    u.x = f2bf((float)q.x * sc);
    u.y = f2bf((float)q.y * sc);
    u.z = f2bf((float)q.z * sc);
    u.w = f2bf((float)q.w * sc);
    *(ushort4*)(Br + (size_t)4 * e) = u;
  }
  if (tid < RANK) Br[IN_F + tid] = f2bf(lu[(size_t)o * RANK + tid]);
  if (tid < 8) {
    ushort4 z; z.x = z.y = z.z = z.w = 0;
    *(ushort4*)(Br + IN_F + 32 + tid * 4) = z;
  }
}

// ---------------- lorad: tr = x @ ld^T, split-K=8 partials ----------------
__global__ __launch_bounds__(256) void lorad_kernel(const float* __restrict__ x,
                                                    const float* __restrict__ ld,
                                                    float* __restrict__ tr8) {
  __shared__ float Xs[128][68];
  __shared__ float Ls[32][68];
  int b = blockIdx.x;
  int t0 = (b >> 3) * 128;
  int kbase = (b & 7) * 512;
  int tid = threadIdx.x;
  int rb = tid & 7;
  int tb = tid >> 3;
  float acc[4][4];
#pragma unroll
  for (int i = 0; i < 4; ++i)
#pragma unroll
    for (int j = 0; j < 4; ++j) acc[i][j] = 0.f;

  for (int kc = 0; kc < 512; kc += 64) {
    int k0 = kbase + kc;
    __syncthreads();
#pragma unroll
    for (int s = 0; s < 8; ++s) {
      int e = tid + s * 256;
      int row = e >> 4, c4 = (e & 15) * 4;
      float4 vv = *(const float4*)(x + (size_t)(t0 + row) * IN_F + k0 + c4);
      *(float4*)&Xs[row][c4] = vv;
    }
#pragma unroll
    for (int s = 0; s < 2; ++s) {
      int e = tid + s * 256;
      int row = e >> 4, c4 = (e & 15) * 4;
      float4 vv = *(const float4*)(ld + (size_t)row * IN_F + k0 + c4);
      *(float4*)&Ls[row][c4] = vv;
    }
    __syncthreads();
    for (int k4 = 0; k4 < 64; k4 += 4) {
      float4 lv[4], xv[4];
#pragma unroll
      for (int r = 0; r < 4; ++r) lv[r] = *(float4*)&Ls[rb + r * 8][k4];
#pragma unroll
      for (int mm = 0; mm < 4; ++mm) xv[mm] = *(float4*)&Xs[tb + mm * 32][k4];
#pragma unroll
      for (int mm = 0; mm < 4; ++mm)
#pragma unroll
        for (int r = 0; r < 4; ++r)
          acc[mm][r] += xv[mm].x * lv[r].x + xv[mm].y * lv[r].y +
                        xv[mm].z * lv[r].z + xv[mm].w * lv[r].w;
    }
  }
  float* dst = tr8 + (size_t)(b & 7) * NTOK * RANK;
#pragma unroll
  for (int mm = 0; mm < 4; ++mm)
#pragma unroll
    for (int r = 0; r < 4; ++r)
      dst[(size_t)(t0 + tb + mm * 32) * RANK + rb + r * 8] = acc[mm][r];
}

// ---------------- trwrite ----------------
__global__ __launch_bounds__(256) void trwrite_kernel(const float* __restrict__ tr8,
                                                      const float* __restrict__ ascale,
                                                      u16* __restrict__ A) {
  int idx = blockIdx.x * 256 + threadIdx.x;
  int t = idx >> 5, r = idx & 31;
  float s = 0.f;
#pragma unroll
  for (int k = 0; k < 8; ++k) s += tr8[(size_t)k * NTOK * RANK + idx];
  A[(size_t)t * KEXT + IN_F + r] = f2bf(s / ascale[t]);
}

// ---------------- main GEMM: 256x256, BK=64, 8 waves, m201-style 8-phase over 2 K-tiles ----------------
// LDS: dbuf d at d*65536: A = 256 rows x 128B linear at +0 (staging halves
// A0=rows 0-127 at +0, A1=rows 128-255 at +16384); B same at +32768.
// Swizzle: 16B chunk u of row r holds global chunk u^(r&7) (pre-swizzled
// global source, linear gload dest, XOR on ds_read) -> 0 bank conflicts (r4).
// Iter u processes tiles T0=2u (dbuf0, phases P1-4) and T1=2u+1 (dbuf1, P5-8).
// Phase = { ds-reads (12/4/8/0); stage half-tiles; [lgkm8]; barrier; lgkm0;
//           setprio1; 16 MFMA (one 64x32 quadrant x K=64); setprio0; barrier }
// Stage slots: P1: A1d1(2u+1) | P3: B0d0,B1d0(2u+2) | P4: A0d0,A1d0(2u+2)
//              P7: B0d1(2u+3) | P8: B1d1,A0d1(2u+3)
// vmcnt(6) at P4 forces {prev P7,P8 + P1} -> dbuf1 complete before P5 reads.
// vmcnt(4) at P8 forces {P3,P4} -> dbuf0 complete before next-iter P1 reads.
// WAR: each staged region's last reader is >=1 phase-end barrier earlier
// (dbuf0.B read P1-2, staged P3; dbuf0.A read P1,P3, staged P4; dbuf1.B read
// P5-6, staged P7-8; dbuf1.A read P5,P7, staged P8,P1').
// Tail: 32 iters cover tiles 0..63; tile 64 (staged u31 P3/P4, drained by u31
// P8's vmcnt(0) since s78=false) runs free-flow with no barriers.

#define PH_SYNC() do { __builtin_amdgcn_sched_barrier(0); \
                       asm volatile("s_barrier" ::: "memory"); \
                       asm volatile("s_waitcnt lgkmcnt(0)" ::: "memory"); \
                       __builtin_amdgcn_sched_barrier(0); } while (0)
#define PH_END() do { __builtin_amdgcn_sched_barrier(0); \
                      asm volatile("s_barrier" ::: "memory"); } while (0)

#define STAGE_A(dbase, H, src) do { \
  const char* s_ = (src) + (size_t)(H) * (128 * ROWB); \
  char* l_ = smem + (dbase) + (H) * 16384 + tid * 16; \
  gload_lds16(s_, l_); \
  gload_lds16(s_ + (size_t)64 * ROWB, l_ + 8192); } while (0)

#define STAGE_B(dbase, H, src) do { \
  const char* s_ = (src) + (size_t)(H) * (128 * ROWB); \
  char* l_ = smem + (dbase) + 32768 + (H) * 16384 + tid * 16; \
  gload_lds16(s_, l_); \
  gload_lds16(s_ + (size_t)64 * ROWB, l_ + 8192); } while (0)

#define READ_A(dst, dbase, h) \
  _Pragma("unroll") for (int i = 0; i < 4; ++i) { \
    dst[i][0] = *(const bf16x8*)(smem + (dbase) + aoff + (h) * 8192 + i * 2048 + colx0); \
    dst[i][1] = *(const bf16x8*)(smem + (dbase) + aoff + (h) * 8192 + i * 2048 + colx1); }

#define READ_B(dst, dbase, uu) \
  _Pragma("unroll") for (int j = 0; j < 2; ++j) { \
    dst[j][0] = *(const bf16x8*)(smem + (dbase) + boff + (uu) * 4096 + j * 2048 + colx0); \
    dst[j][1] = *(const bf16x8*)(smem + (dbase) + boff + (uu) * 4096 + j * 2048 + colx1); }

#define MFMAQ(aS, bU, ib, jb) \
  __builtin_amdgcn_s_setprio(1); \
  _Pragma("unroll") for (int i = 0; i < 4; ++i) \
  _Pragma("unroll") for (int j = 0; j < 2; ++j) { \
    acc[(ib)+i][(jb)+j] = __builtin_amdgcn_mfma_f32_16x16x32_bf16(aS[i][0], bU[j][0], acc[(ib)+i][(jb)+j], 0, 0, 0); \
    acc[(ib)+i][(jb)+j] = __builtin_amdgcn_mfma_f32_16x16x32_bf16(aS[i][1], bU[j][1], acc[(ib)+i][(jb)+j], 0, 0, 0); } \
  __builtin_amdgcn_s_setprio(0);

__global__ __launch_bounds__(512, 2) void gemm_kernel(const u16* __restrict__ A,
                                                      const u16* __restrict__ B,
                                                      const float* __restrict__ ascale,
                                                      const float* __restrict__ bias,
                                                      float* __restrict__ out) {
  __shared__ __align__(16) char smem[131072];
  int b = blockIdx.x;
  int swz = (b & 7) * 32 + (b >> 3);     // 256 blocks, 8 XCDs -> bijective
  int by = swz >> 4, bx = swz & 15;
  int tm = by * 256, tn = bx * 256;
  int tid = threadIdx.x;
  int lane = tid & 63, wid = tid >> 6;
  int wr = wid >> 2, wc = wid & 3;       // 2x4 wave grid; wave owns 128x64 of C
  int l15 = lane & 15, l4 = lane >> 4;
  int xorb = (l15 & 7) << 4;             // row&7 -> 16B-chunk XOR (bits 4-6)
  int colx0 = (l4 * 16) ^ xorb;
  int colx1 = (l4 * 16 + 64) ^ xorb;
  int aoff = wr * 16384 + l15 * 128;     // A row = wr*128 + h*64 + i*16 + l15
  int boff = 32768 + wc * 8192 + l15 * 128;  // B row = wc*64 + uu*32 + j*16 + l15

  // staging source base: thread covers rows (tid>>3) + {0,64}, pre-swizzled chunk
  int cb = (((tid & 7) ^ ((tid >> 3) & 7)) << 4);
  const char* ag = (const char*)A + (size_t)(tm + (tid >> 3)) * ROWB + cb;
  const char* bg = (const char*)B + (size_t)(tn + (tid >> 3)) * ROWB + cb;

  f32x4 acc[8][4];
#pragma unroll
  for (int i = 0; i < 8; ++i)
#pragma unroll
    for (int j = 0; j < 4; ++j) acc[i][j] = (f32x4){0.f, 0.f, 0.f, 0.f};

  // prologue: tile0 full -> dbuf0; tile1 B halves + A0 -> dbuf1 (steady-state image)
  STAGE_A(0, 0, ag);  STAGE_A(0, 1, ag);
  STAGE_B(0, 0, bg);  STAGE_B(0, 1, bg);
  STAGE_B(D1, 0, bg + 128);  STAGE_B(D1, 1, bg + 128);
  STAGE_A(D1, 0, ag + 128);
  asm volatile("s_waitcnt vmcnt(6)" ::: "memory");  // tile0 landed; tile1 parts in flight
  PH_END();

  const char* agT = ag;   // tile 2u base (+= 256 per iter)
  const char* bgT = bg;
  bf16x8 aS0[4][2], aS1[4][2], bU0[2][2], bU1[2][2];

  for (int u = 0; u < 32; ++u) {
    bool s78 = (2 * u + 3) < NT;   // tile 2u+3 exists?

    // ---- P1: reads S0,U0 of T0 (12); stage A1d1 (tile 2u+1) ----
    READ_A(aS0, 0, 0);
    READ_B(bU0, 0, 0);
    STAGE_A(D1, 1, agT + 128);
    asm volatile("s_waitcnt lgkmcnt(8)" ::: "memory");
    PH_SYNC();
    MFMAQ(aS0, bU0, 0, 0);
    PH_END();

    // ---- P2: reads U1 of T0 (4) ----
    READ_B(bU1, 0, 1);
    PH_SYNC();
    MFMAQ(aS0, bU1, 0, 2);
    PH_END();

    // ---- P3: reads S1 of T0 (8); stage B0d0,B1d0 (tile 2u+2) ----
    READ_A(aS1, 0, 1);
    STAGE_B(0, 0, bgT + 256);
    STAGE_B(0, 1, bgT + 256);
    PH_SYNC();
    MFMAQ(aS1, bU1, 4, 2);
    PH_END();

    // ---- P4: no reads; stage A0d0,A1d0 (tile 2u+2); vmcnt(6) ----
    STAGE_A(0, 0, agT + 256);
    STAGE_A(0, 1, agT + 256);
    asm volatile("s_waitcnt vmcnt(6)" ::: "memory");  // forces prev P7,P8 + P1 -> dbuf1 ready
    PH_SYNC();
    MFMAQ(aS1, bU0, 4, 0);
    PH_END();

    // ---- P5: reads S0,U0 of T1 (12) ----
    READ_A(aS0, D1, 0);
    READ_B(bU0, D1, 0);
    asm volatile("s_waitcnt lgkmcnt(8)" ::: "memory");
    PH_SYNC();
    MFMAQ(aS0, bU0, 0, 0);
    PH_END();

    // ---- P6: reads U1 of T1 (4) ----
    READ_B(bU1, D1, 1);
    PH_SYNC();
    MFMAQ(aS0, bU1, 0, 2);
    PH_END();

    // ---- P7: reads S1 of T1 (8); stage B0d1 (tile 2u+3) ----
    READ_A(aS1, D1, 1);
    if (s78) STAGE_B(D1, 0, bgT + 384);
    PH_SYNC();
    MFMAQ(aS1, bU1, 4, 2);
    PH_END();

    // ---- P8: no reads; stage B1d1,A0d1 (tile 2u+3); vmcnt ----
    if (s78) {
      STAGE_B(D1, 1, bgT + 384);
      STAGE_A(D1, 0, agT + 384);
      asm volatile("s_waitcnt vmcnt(4)" ::: "memory");  // forces P3,P4 -> dbuf0 ready
    } else {
      asm volatile("s_waitcnt vmcnt(0)" ::: "memory");  // tail: drain everything
    }
    PH_SYNC();
    MFMAQ(aS1, bU0, 4, 0);
    PH_END();

    agT += 256;
    bgT += 256;
  }

  // ---- tail: tile 64 from dbuf0, free-flow (staged u31 P3/P4, drained u31 P8) ----
  READ_A(aS0, 0, 0);
  READ_B(bU0, 0, 0);
  READ_A(aS1, 0, 1);
  READ_B(bU1, 0, 1);
  MFMAQ(aS0, bU0, 0, 0);
  MFMAQ(aS0, bU1, 0, 2);
  MFMAQ(aS1, bU1, 4, 2);
  MFMAQ(aS1, bU0, 4, 0);

  // ---- epilogue: C = acc * ascale[row] + bias[col] ----
#pragma unroll
  for (int i = 0; i < 8; ++i) {
    int rowb = tm + wr * 128 + i * 16 + l4 * 4;
#pragma unroll
    for (int j = 0; j < 4; ++j) {
      int col = tn + wc * 64 + j * 16 + l15;
      float bv = bias[col];
#pragma unroll
      for (int q = 0; q < 4; ++q)
        out[(size_t)(rowb + q) * OUT_F + col] = acc[i][j][q] * ascale[rowb + q] + bv;
    }
  }
}

extern "C" void kernel_launch(void* const* d_in, const int* in_sizes, int n_in,
                              void* d_out, int out_size, void* d_ws, size_t ws_size,
                              hipStream_t stream) {
  const float* x = (const float*)d_in[0];
  const int* qw = (const int*)d_in[1];
  const float* wscale = (const float*)d_in[2];
  const float* ld = (const float*)d_in[3];
  const float* lu = (const float*)d_in[4];
  const float* bias = (const float*)d_in[5];
  float* out = (float*)d_out;

  char* ws = (char*)d_ws;
  const size_t szA = (size_t)NTOK * KEXT * sizeof(u16);
  const size_t szB = (size_t)OUT_F * KEXT * sizeof(u16);
  u16* Aext = (u16*)ws;
  u16* Bext = (u16*)(ws + szA);
  float* ascale = (float*)(ws + szA + szB);
  float* tr8 = (float*)(ws + szA + szB + 16384);

  prep_kernel<<<NTOK, 256, 0, stream>>>(x, Aext, ascale);
  dequant_kernel<<<OUT_F, 256, 0, stream>>>(qw, wscale, lu, Bext);
  lorad_kernel<<<256, 256, 0, stream>>>(x, ld, tr8);
  trwrite_kernel<<<NTOK * RANK / 256, 256, 0, stream>>>(tr8, ascale, Aext);
  gemm_kernel<<<(NTOK / 256) * (OUT_F / 256), 512, 0, stream>>>(Aext, Bext, ascale, bias, out);
}